// Round 9
// baseline (188.677 us; speedup 1.0000x reference)
//
#include <hip/hip_runtime.h>

// SimpleDHSRNN fused forward, round 9: cell fusion + cross-layer pipeline +
// BRANCH-SPLIT across 8 waves (4 waves/SIMD at constant total work).
// Block = 512 thr = 8 waves, M=16 rows, grid = 512 (2 blocks/CU).
// Wave w: L2 n-tile (w&3), branch (w>>2): 9 MFMA. Waves 4-7 also run L1(t+1)
// slot (nt=(w-4)&1, br=(w-4)>>1): 3 MFMA. Branch partials (f32x4/lane) exchanged
// via lane-aligned ds_write_b128/ds_read_b128; combine+pack by a-branch waves.
// 2 barriers/step.

typedef float f32x4 __attribute__((ext_vector_type(4)));
typedef short s16x8 __attribute__((ext_vector_type(8)));

#define MFMA16(a, b, c) __builtin_amdgcn_mfma_f32_16x16x32_bf16((a), (b), (c), 0, 0, 0)
#define T_STEPS 196
#define S1S 40    // H1 plane row stride (ushorts)
#define S2S 72    // H2 plane row stride (ushorts)
#define H1B (16 * S1S)
#define H2B (16 * S2S)

// d_ws layout (floats)
#define WS_M1H 0        // [2][32][32]  M1 h-columns (fused W1o·W1b)
#define WS_M1X 2048     // [2][32]      M1 x-column
#define WS_C1  2112     // [2][32]      fused bias W1o_k · r1_bb[k]
#define WS_M2  2176     // [2][64][96]  M2 (fused W2o·W2b)
#define WS_C2  14464    // [2][64]      fused bias
#define WS_TOTAL 14592

__global__ void prep_fuse(const float* __restrict__ r1_bw, const float* __restrict__ r1_bb,
                          const float* __restrict__ r1_ow, const float* __restrict__ r2_bw,
                          const float* __restrict__ r2_bb, const float* __restrict__ r2_ow,
                          float* __restrict__ ws)
{
    int idx = blockIdx.x * 256 + threadIdx.x;
    if (idx >= WS_TOTAL) return;
    float acc = 0.0f;
    if (idx < WS_M1X) {                     // M1h[kb][n][k]
        int kb = idx >> 10, rem = idx & 1023, n = rem >> 5, k = rem & 31;
        for (int j = 0; j < 32; ++j)
            acc += r1_ow[n * 64 + kb * 32 + j] * r1_bw[(kb * 32 + j) * 33 + 1 + k];
    } else if (idx < WS_C1) {               // m1x[kb][n]
        int r = idx - WS_M1X; int kb = r >> 5, n = r & 31;
        for (int j = 0; j < 32; ++j)
            acc += r1_ow[n * 64 + kb * 32 + j] * r1_bw[(kb * 32 + j) * 33];
    } else if (idx < WS_M2) {               // c1[kb][n]
        int r = idx - WS_C1; int kb = r >> 5, n = r & 31;
        for (int j = 0; j < 32; ++j)
            acc += r1_ow[n * 64 + kb * 32 + j] * r1_bb[kb * 32 + j];
    } else if (idx < WS_C2) {               // M2[kb][n][k]
        int r = idx - WS_M2; int kb = r / 6144; int r2 = r - kb * 6144;
        int n = r2 / 96, k = r2 - n * 96;
        for (int j = 0; j < 64; ++j)
            acc += r2_ow[n * 128 + kb * 64 + j] * r2_bw[(kb * 64 + j) * 96 + k];
    } else {                                // c2[kb][n]
        int r = idx - WS_C2; int kb = r >> 6, n = r & 63;
        for (int j = 0; j < 64; ++j)
            acc += r2_ow[n * 128 + kb * 64 + j] * r2_bb[kb * 64 + j];
    }
    ws[idx] = acc;
}

// 3-term split: a ~= h + l as bf16 pair
__device__ __forceinline__ void split8g(const float* __restrict__ p, s16x8& h, s16x8& l) {
#pragma unroll
    for (int i = 0; i < 8; ++i) {
        float v = p[i];
        unsigned b = __float_as_uint(v);
        float lo = v - __uint_as_float(b & 0xFFFF0000u);
        h[i] = (short)(b >> 16);
        l[i] = (short)(__float_as_uint(lo) >> 16);
    }
}

__global__ __launch_bounds__(512, 4)
void dhsrnn_bsplit(const float* __restrict__ x, const float* __restrict__ ws,
                   const float* __restrict__ r1_ob, const float* __restrict__ r2_ob,
                   const float* __restrict__ cw, const float* __restrict__ cb,
                   float* __restrict__ out)
{
    __shared__ __align__(16) unsigned short H1h[2 * H1B], H1l[2 * H1B];
    __shared__ __align__(16) unsigned short H2h[2 * H2B], H2l[2 * H2B];
    __shared__ float XBuf[2][16];
    __shared__ float hcf[16 * 68];        // fp32 h2(T-1) for classifier
    __shared__ __align__(16) f32x4 P2[4 * 64];   // L2 b-branch partials, lane-aligned
    __shared__ __align__(16) f32x4 P1[2 * 64];   // L1 b-branch partials

    const int tid = threadIdx.x;
    const int w   = tid >> 6;     // 0..7
    const int l   = tid & 63;
    const int li  = l & 15;
    const int g   = l >> 4;
    const int row0 = blockIdx.x * 16;

    // ---- L2 role: n-tile nt2 = w&3, branch br2 = w>>2 ----
    const int nt2 = w & 3, br2 = w >> 2;
    const int n4  = nt2 * 16 + li;
    s16x8 B2h[3], B2l[3];
#pragma unroll
    for (int kt = 0; kt < 3; ++kt)
        split8g(ws + WS_M2 + br2 * 6144 + n4 * 96 + kt * 32 + g * 8, B2h[kt], B2l[kt]);
    const float c2   = ws[WS_C2 + br2 * 64 + n4];
    const float al2  = br2 ? 0.7f : 0.3f;
    const float om2  = br2 ? 0.3f : 0.7f;
    const float ob2n = r2_ob[n4];          // used by a-waves (combiners)

    // ---- L1 role (waves 4-7): nt1 = (w-4)&1, br1 = (w-4)>>1 ----
    const int i1 = w - 4;
    const int nt1 = i1 & 1, br1 = (i1 >> 1) & 1;
    const int n2 = nt1 * 16 + li;
    s16x8 B1h, B1l;
    float m1x = 0.f, c1 = 0.f, al1 = 0.3f, om1 = 0.7f, ob1n = 0.f;
    if (w >= 4) {
        split8g(ws + WS_M1H + br1 * 1024 + n2 * 32 + g * 8, B1h, B1l);
        m1x  = ws[WS_M1X + br1 * 32 + n2];
        c1   = ws[WS_C1 + br1 * 32 + n2];
        al1  = br1 ? 0.7f : 0.3f;
        om1  = br1 ? 0.3f : 0.7f;
        ob1n = r1_ob[n2];
    }

    // persistent per-branch EMA-projected states (fp32, acc layout m = 4g + r)
    f32x4 v2 = {0.f, 0.f, 0.f, 0.f};   // own L2 branch
    f32x4 v1 = {0.f, 0.f, 0.f, 0.f};   // own L1 branch (waves 4-7)

    // ---- init: zero h2 buf0, stage x(0),x(1) ----
    for (int i = tid; i < H2B; i += 512) { H2h[i] = 0; H2l[i] = 0; }
    if (tid < 16) {
        XBuf[0][tid] = x[(row0 + tid) * 784];
        XBuf[1][tid] = x[(row0 + tid) * 784 + 4];
    }
    __syncthreads();

    // ---- prologue: h1(0) = relu(v1a + v1b + ob1), v1 = om1*(c1 + m1x*x0) ----
    if (w >= 4) {
        const f32x4 xv = *reinterpret_cast<const f32x4*>(&XBuf[0][4 * g]);
#pragma unroll
        for (int r = 0; r < 4; ++r) {
            float z = c1 + m1x * xv[r];
            v1[r] = om1 * z;
        }
        if (br1) P1[nt1 * 64 + l] = v1;
    }
    __syncthreads();
    if (w == 4 || w == 5) {
        const f32x4 pb = P1[nt1 * 64 + l];
#pragma unroll
        for (int r = 0; r < 4; ++r) {
            int m = 4 * g + r;
            float h = fmaxf(v1[r] + pb[r] + ob1n, 0.0f);
            unsigned b = __float_as_uint(h);
            float lo = h - __uint_as_float(b & 0xFFFF0000u);
            H1h[m * S1S + n2] = (unsigned short)(b >> 16);
            H1l[m * S1S + n2] = (unsigned short)(__float_as_uint(lo) >> 16);
        }
    }
    __syncthreads();

    // ---- pipelined loop: step t = L2(t) + L1(t+1) ----
#pragma unroll 1
    for (int t = 0; t < T_STEPS; ++t) {
        const int rb = (t & 1);
        const int wb = rb ^ 1;

        // x(t+2) prefetch (wave 0)
        float xnext = 0.0f;
        if (w == 0 && l < 16 && t < T_STEPS - 2)
            xnext = x[(row0 + l) * 784 + 4 * (t + 2)];

        // A-frags: h1(t) tile + 2 h2(t-1) tiles
        const s16x8 a1h = *reinterpret_cast<const s16x8*>(&H1h[rb * H1B + li * S1S + g * 8]);
        const s16x8 a1l = *reinterpret_cast<const s16x8*>(&H1l[rb * H1B + li * S1S + g * 8]);
        const s16x8 a2h1 = *reinterpret_cast<const s16x8*>(&H2h[rb * H2B + li * S2S + g * 8]);
        const s16x8 a2l1 = *reinterpret_cast<const s16x8*>(&H2l[rb * H2B + li * S2S + g * 8]);
        const s16x8 a2h2 = *reinterpret_cast<const s16x8*>(&H2h[rb * H2B + li * S2S + 32 + g * 8]);
        const s16x8 a2l2 = *reinterpret_cast<const s16x8*>(&H2l[rb * H2B + li * S2S + 32 + g * 8]);

        // ---- phase 1: L2(t), one branch per wave, 9 MFMA in 2 chains ----
        {
            f32x4 d0 = {0.f, 0.f, 0.f, 0.f};
            f32x4 d1 = {0.f, 0.f, 0.f, 0.f};
            d0 = MFMA16(a1h,  B2h[0], d0);
            d1 = MFMA16(a1l,  B2h[0], d1);
            d0 = MFMA16(a1h,  B2l[0], d0);
            d1 = MFMA16(a2h1, B2h[1], d1);
            d0 = MFMA16(a2l1, B2h[1], d0);
            d1 = MFMA16(a2h1, B2l[1], d1);
            d0 = MFMA16(a2h2, B2h[2], d0);
            d1 = MFMA16(a2l2, B2h[2], d1);
            d0 = MFMA16(a2h2, B2l[2], d0);
#pragma unroll
            for (int r = 0; r < 4; ++r) {
                float z = d0[r] + d1[r] + c2;
                v2[r] = al2 * v2[r] + om2 * z;
            }
        }
        if (w >= 4) {
            P2[nt2 * 64 + l] = v2;           // b-branch L2 partial
            if (t < T_STEPS - 1) {
                // L1(t+1), one (nt,branch) slot per wave, 3 MFMA
                f32x4 e0 = {0.f, 0.f, 0.f, 0.f};
                e0 = MFMA16(a1h, B1h, e0);
                e0 = MFMA16(a1l, B1h, e0);
                e0 = MFMA16(a1h, B1l, e0);
                const f32x4 xv = *reinterpret_cast<const f32x4*>(&XBuf[wb][4 * g]);  // x(t+1)
#pragma unroll
                for (int r = 0; r < 4; ++r) {
                    float z = e0[r] + c1 + m1x * xv[r];
                    v1[r] = al1 * v1[r] + om1 * z;
                }
                if (br1) P1[nt1 * 64 + l] = v1;   // b-branch L1 partial
            }
        }
        __syncthreads();   // #1: partials ready

        // ---- phase 2: combine + pack + write (a-branch waves) ----
        if (w < 4) {
            const f32x4 pb = P2[nt2 * 64 + l];
#pragma unroll
            for (int r = 0; r < 4; ++r) {
                int m = 4 * g + r;
                float h = fmaxf(v2[r] + pb[r] + ob2n, 0.0f);
                unsigned b = __float_as_uint(h);
                float lo = h - __uint_as_float(b & 0xFFFF0000u);
                H2h[wb * H2B + m * S2S + n4] = (unsigned short)(b >> 16);
                H2l[wb * H2B + m * S2S + n4] = (unsigned short)(__float_as_uint(lo) >> 16);
                if (t == T_STEPS - 1) hcf[m * 68 + n4] = h;
            }
        } else if ((w == 4 || w == 5) && t < T_STEPS - 1) {
            const f32x4 pb = P1[nt1 * 64 + l];
#pragma unroll
            for (int r = 0; r < 4; ++r) {
                int m = 4 * g + r;
                float h = fmaxf(v1[r] + pb[r] + ob1n, 0.0f);
                unsigned b = __float_as_uint(h);
                float lo = h - __uint_as_float(b & 0xFFFF0000u);
                H1h[wb * H1B + m * S1S + n2] = (unsigned short)(b >> 16);
                H1l[wb * H1B + m * S1S + n2] = (unsigned short)(__float_as_uint(lo) >> 16);
            }
        }
        if (w == 0 && l < 16 && t < T_STEPS - 2) XBuf[rb][l] = xnext;   // commit x(t+2)
        __syncthreads();   // #2: h1(t+1), h2(t), x(t+2) ready
    }

    // ---- classifier: out[b][c] = h2 . cw[c] + cb[c] ----
    {
        const int c = tid >> 4;
        const int e = tid & 15;
        if (c < 10) {
            float acc = cb[c];
#pragma unroll 4
            for (int dd = 0; dd < 64; ++dd)
                acc += hcf[e * 68 + dd] * cw[c * 64 + dd];
            out[(row0 + e) * 10 + c] = acc;
        }
    }
}

extern "C" void kernel_launch(void* const* d_in, const int* in_sizes, int n_in,
                              void* d_out, int out_size, void* d_ws, size_t ws_size,
                              hipStream_t stream) {
    const float* x     = (const float*)d_in[0];
    const float* r1_bw = (const float*)d_in[1];
    const float* r1_bb = (const float*)d_in[2];
    const float* r1_ow = (const float*)d_in[3];
    const float* r1_ob = (const float*)d_in[4];
    const float* r2_bw = (const float*)d_in[5];
    const float* r2_bb = (const float*)d_in[6];
    const float* r2_ow = (const float*)d_in[7];
    const float* r2_ob = (const float*)d_in[8];
    const float* cw    = (const float*)d_in[9];
    const float* cb    = (const float*)d_in[10];
    float* ws  = (float*)d_ws;
    float* out = (float*)d_out;

    hipLaunchKernelGGL(prep_fuse, dim3((WS_TOTAL + 255) / 256), dim3(256), 0, stream,
                       r1_bw, r1_bb, r1_ow, r2_bw, r2_bb, r2_ow, ws);
    hipLaunchKernelGGL(dhsrnn_bsplit, dim3(512), dim3(512), 0, stream,
                       x, ws, r1_ob, r2_ob, cw, cb, out);
}

// Round 10
// 187.329 us; speedup vs baseline: 1.0072x; 1.0072x over previous
//
#include <hip/hip_runtime.h>

// SimpleDHSRNN fused forward, round 10: round-8 pipeline + ALL x staged to LDS
// upfront -> zero VMEM ops (and no vmcnt drain) inside the 196-step loop.
// Block = 256 thr = 4 waves, M=16 rows, grid = 512 (2 blocks/CU).
// Step t: L2(t) on all waves; L1(t+1) on waves 2,3; ONE barrier/step.

typedef float f32x4 __attribute__((ext_vector_type(4)));
typedef short s16x8 __attribute__((ext_vector_type(8)));

#define MFMA16(a, b, c) __builtin_amdgcn_mfma_f32_16x16x32_bf16((a), (b), (c), 0, 0, 0)
#define T_STEPS 196
#define S1S 40    // H1 plane row stride (ushorts)
#define S2S 72    // H2 plane row stride (ushorts)
#define H1B (16 * S1S)
#define H2B (16 * S2S)

// d_ws layout (floats)
#define WS_M1H 0        // [2][32][32]  M1 h-columns (fused W1o·W1b)
#define WS_M1X 2048     // [2][32]      M1 x-column
#define WS_C1  2112     // [2][32]      fused bias W1o_k · r1_bb[k]
#define WS_M2  2176     // [2][64][96]  M2 (fused W2o·W2b)
#define WS_C2  14464    // [2][64]      fused bias
#define WS_TOTAL 14592

__global__ void prep_fuse(const float* __restrict__ r1_bw, const float* __restrict__ r1_bb,
                          const float* __restrict__ r1_ow, const float* __restrict__ r2_bw,
                          const float* __restrict__ r2_bb, const float* __restrict__ r2_ow,
                          float* __restrict__ ws)
{
    int idx = blockIdx.x * 256 + threadIdx.x;
    if (idx >= WS_TOTAL) return;
    float acc = 0.0f;
    if (idx < WS_M1X) {                     // M1h[kb][n][k]
        int kb = idx >> 10, rem = idx & 1023, n = rem >> 5, k = rem & 31;
        for (int j = 0; j < 32; ++j)
            acc += r1_ow[n * 64 + kb * 32 + j] * r1_bw[(kb * 32 + j) * 33 + 1 + k];
    } else if (idx < WS_C1) {               // m1x[kb][n]
        int r = idx - WS_M1X; int kb = r >> 5, n = r & 31;
        for (int j = 0; j < 32; ++j)
            acc += r1_ow[n * 64 + kb * 32 + j] * r1_bw[(kb * 32 + j) * 33];
    } else if (idx < WS_M2) {               // c1[kb][n]
        int r = idx - WS_C1; int kb = r >> 5, n = r & 31;
        for (int j = 0; j < 32; ++j)
            acc += r1_ow[n * 64 + kb * 32 + j] * r1_bb[kb * 32 + j];
    } else if (idx < WS_C2) {               // M2[kb][n][k]
        int r = idx - WS_M2; int kb = r / 6144; int r2 = r - kb * 6144;
        int n = r2 / 96, k = r2 - n * 96;
        for (int j = 0; j < 64; ++j)
            acc += r2_ow[n * 128 + kb * 64 + j] * r2_bw[(kb * 64 + j) * 96 + k];
    } else {                                // c2[kb][n]
        int r = idx - WS_C2; int kb = r >> 6, n = r & 63;
        for (int j = 0; j < 64; ++j)
            acc += r2_ow[n * 128 + kb * 64 + j] * r2_bb[kb * 64 + j];
    }
    ws[idx] = acc;
}

// 3-term split: a ~= h + l as bf16 pair
__device__ __forceinline__ void split8g(const float* __restrict__ p, s16x8& h, s16x8& l) {
#pragma unroll
    for (int i = 0; i < 8; ++i) {
        float v = p[i];
        unsigned b = __float_as_uint(v);
        float lo = v - __uint_as_float(b & 0xFFFF0000u);
        h[i] = (short)(b >> 16);
        l[i] = (short)(__float_as_uint(lo) >> 16);
    }
}

__global__ __launch_bounds__(256, 2)
void dhsrnn_pipe(const float* __restrict__ x, const float* __restrict__ ws,
                 const float* __restrict__ r1_ob, const float* __restrict__ r2_ob,
                 const float* __restrict__ cw, const float* __restrict__ cb,
                 float* __restrict__ out)
{
    __shared__ __align__(16) unsigned short H1h[2 * H1B], H1l[2 * H1B];
    __shared__ __align__(16) unsigned short H2h[2 * H2B], H2l[2 * H2B];
    __shared__ __align__(16) float XAll[T_STEPS * 16];   // [t][row] 12.25 KB
    __shared__ float hcf[16 * 68];   // fp32 h2(T-1) for classifier

    const int tid = threadIdx.x;
    const int w   = tid >> 6;
    const int l   = tid & 63;
    const int li  = l & 15;
    const int g   = l >> 4;
    const int row0 = blockIdx.x * 16;

    // ---- stage ALL x for this block: XAll[t*16 + e] = x[(row0+e)*784 + 4t] ----
    for (int i = tid; i < 16 * T_STEPS; i += 256) {
        int e = i / T_STEPS;
        int t = i - e * T_STEPS;
        XAll[t * 16 + e] = x[(row0 + e) * 784 + 4 * t];
    }

    // ---- L2 weights (all waves): fused layer-2, N=64, K=96 ----
    const int n4 = w * 16 + li;
    s16x8 B2ah[3], B2al[3], B2bh[3], B2bl[3];
#pragma unroll
    for (int kt = 0; kt < 3; ++kt) {
        split8g(ws + WS_M2 + 0 * 6144 + n4 * 96 + kt * 32 + g * 8, B2ah[kt], B2al[kt]);
        split8g(ws + WS_M2 + 1 * 6144 + n4 * 96 + kt * 32 + g * 8, B2bh[kt], B2bl[kt]);
    }
    const float c2a = ws[WS_C2 + n4], c2b = ws[WS_C2 + 64 + n4];
    const float ob2n = r2_ob[n4];

    // ---- L1 weights (waves 2,3): fused layer-1, N=32, K=32 ----
    const int n2 = (w & 1) * 16 + li;    // used on w>=2
    s16x8 B1ah, B1al, B1bh, B1bl;
    float m1xa = 0.f, m1xb = 0.f, c1a = 0.f, c1b = 0.f, ob1n = 0.f;
    if (w >= 2) {
        split8g(ws + WS_M1H + 0 * 1024 + n2 * 32 + g * 8, B1ah, B1al);
        split8g(ws + WS_M1H + 1 * 1024 + n2 * 32 + g * 8, B1bh, B1bl);
        m1xa = ws[WS_M1X + n2];      m1xb = ws[WS_M1X + 32 + n2];
        c1a  = ws[WS_C1 + n2];       c1b  = ws[WS_C1 + 32 + n2];
        ob1n = r1_ob[n2];
    }

    // EMA states (fp32, acc layout m = 4g + r)
    f32x4 va  = {0.f, 0.f, 0.f, 0.f}, vb  = {0.f, 0.f, 0.f, 0.f};     // layer1 (w>=2)
    f32x4 va2 = {0.f, 0.f, 0.f, 0.f}, vb2 = {0.f, 0.f, 0.f, 0.f};     // layer2 (all)

    // ---- prologue: zero h2 buf0; compute h1(0) into H1 buf0 ----
    for (int i = tid; i < H2B; i += 256) { H2h[i] = 0; H2l[i] = 0; }
    __syncthreads();
    if (w >= 2) {
        const f32x4 xv = *reinterpret_cast<const f32x4*>(&XAll[4 * g]);   // x(0)
#pragma unroll
        for (int r = 0; r < 4; ++r) {
            int m = 4 * g + r;
            float za = c1a + m1xa * xv[r];
            va[r] = 0.7f * za;                  // alpha_a = 0.3, s=0
            float zb = c1b + m1xb * xv[r];
            vb[r] = 0.3f * zb;                  // alpha_b = 0.7
            float h = fmaxf(va[r] + vb[r] + ob1n, 0.0f);
            unsigned b = __float_as_uint(h);
            float lo = h - __uint_as_float(b & 0xFFFF0000u);
            H1h[m * S1S + n2] = (unsigned short)(b >> 16);
            H1l[m * S1S + n2] = (unsigned short)(__float_as_uint(lo) >> 16);
        }
    }
    __syncthreads();

    // ---- pipelined loop: iteration t computes L2(t) and (t<195) L1(t+1) ----
    // NO VMEM ops inside this loop.
#pragma unroll 1
    for (int t = 0; t < T_STEPS; ++t) {
        const int rb  = (t & 1);
        const int wb  = rb ^ 1;

        // shared A-frag: h1(t) (kt0 of L2; also A of L1)
        const s16x8 a1h = *reinterpret_cast<const s16x8*>(&H1h[rb * H1B + li * S1S + g * 8]);
        const s16x8 a1l = *reinterpret_cast<const s16x8*>(&H1l[rb * H1B + li * S1S + g * 8]);

        // ---- L2(t): all waves ----
        {
            f32x4 d = {0.f, 0.f, 0.f, 0.f};
            f32x4 e = {0.f, 0.f, 0.f, 0.f};
            d = MFMA16(a1h, B2ah[0], d);
            d = MFMA16(a1l, B2ah[0], d);
            d = MFMA16(a1h, B2al[0], d);
            e = MFMA16(a1h, B2bh[0], e);
            e = MFMA16(a1l, B2bh[0], e);
            e = MFMA16(a1h, B2bl[0], e);
            {   // kt1: h2(t-1)[0:32]
                const s16x8 ah = *reinterpret_cast<const s16x8*>(&H2h[rb * H2B + li * S2S + g * 8]);
                const s16x8 al = *reinterpret_cast<const s16x8*>(&H2l[rb * H2B + li * S2S + g * 8]);
                d = MFMA16(ah, B2ah[1], d);
                d = MFMA16(al, B2ah[1], d);
                d = MFMA16(ah, B2al[1], d);
                e = MFMA16(ah, B2bh[1], e);
                e = MFMA16(al, B2bh[1], e);
                e = MFMA16(ah, B2bl[1], e);
            }
            {   // kt2: h2(t-1)[32:64]
                const s16x8 ah = *reinterpret_cast<const s16x8*>(&H2h[rb * H2B + li * S2S + 32 + g * 8]);
                const s16x8 al = *reinterpret_cast<const s16x8*>(&H2l[rb * H2B + li * S2S + 32 + g * 8]);
                d = MFMA16(ah, B2ah[2], d);
                d = MFMA16(al, B2ah[2], d);
                d = MFMA16(ah, B2al[2], d);
                e = MFMA16(ah, B2bh[2], e);
                e = MFMA16(al, B2bh[2], e);
                e = MFMA16(ah, B2bl[2], e);
            }
#pragma unroll
            for (int r = 0; r < 4; ++r) {
                int m = 4 * g + r;
                float za = d[r] + c2a;
                va2[r] = 0.3f * va2[r] + 0.7f * za;
                float zb = e[r] + c2b;
                vb2[r] = 0.7f * vb2[r] + 0.3f * zb;
                float h = fmaxf(va2[r] + vb2[r] + ob2n, 0.0f);
                unsigned b = __float_as_uint(h);
                float lo = h - __uint_as_float(b & 0xFFFF0000u);
                H2h[wb * H2B + m * S2S + n4] = (unsigned short)(b >> 16);
                H2l[wb * H2B + m * S2S + n4] = (unsigned short)(__float_as_uint(lo) >> 16);
                if (t == T_STEPS - 1) hcf[m * 68 + n4] = h;
            }
        }

        // ---- L1(t+1): waves 2,3 (reuse a1h/a1l) ----
        if (w >= 2 && t < T_STEPS - 1) {
            f32x4 d = {0.f, 0.f, 0.f, 0.f};
            f32x4 e = {0.f, 0.f, 0.f, 0.f};
            d = MFMA16(a1h, B1ah, d);
            d = MFMA16(a1l, B1ah, d);
            d = MFMA16(a1h, B1al, d);
            e = MFMA16(a1h, B1bh, e);
            e = MFMA16(a1l, B1bh, e);
            e = MFMA16(a1h, B1bl, e);
            const f32x4 xv = *reinterpret_cast<const f32x4*>(&XAll[(t + 1) * 16 + 4 * g]);  // x(t+1)
#pragma unroll
            for (int r = 0; r < 4; ++r) {
                int m = 4 * g + r;
                float za = d[r] + c1a + m1xa * xv[r];
                va[r] = 0.3f * va[r] + 0.7f * za;
                float zb = e[r] + c1b + m1xb * xv[r];
                vb[r] = 0.7f * vb[r] + 0.3f * zb;
                float h = fmaxf(va[r] + vb[r] + ob1n, 0.0f);
                unsigned b = __float_as_uint(h);
                float lo = h - __uint_as_float(b & 0xFFFF0000u);
                H1h[wb * H1B + m * S1S + n2] = (unsigned short)(b >> 16);
                H1l[wb * H1B + m * S1S + n2] = (unsigned short)(__float_as_uint(lo) >> 16);
            }
        }

        __syncthreads();   // h1(t+1), h2(t) ready
    }

    // ---- classifier: out[b][c] = h2 . cw[c] + cb[c] ----
    {
        const int c = tid >> 4;
        const int e = tid & 15;
        if (c < 10) {
            float acc = cb[c];
#pragma unroll 4
            for (int dd = 0; dd < 64; ++dd)
                acc += hcf[e * 68 + dd] * cw[c * 64 + dd];
            out[(row0 + e) * 10 + c] = acc;
        }
    }
}

extern "C" void kernel_launch(void* const* d_in, const int* in_sizes, int n_in,
                              void* d_out, int out_size, void* d_ws, size_t ws_size,
                              hipStream_t stream) {
    const float* x     = (const float*)d_in[0];
    const float* r1_bw = (const float*)d_in[1];
    const float* r1_bb = (const float*)d_in[2];
    const float* r1_ow = (const float*)d_in[3];
    const float* r1_ob = (const float*)d_in[4];
    const float* r2_bw = (const float*)d_in[5];
    const float* r2_bb = (const float*)d_in[6];
    const float* r2_ow = (const float*)d_in[7];
    const float* r2_ob = (const float*)d_in[8];
    const float* cw    = (const float*)d_in[9];
    const float* cb    = (const float*)d_in[10];
    float* ws  = (float*)d_ws;
    float* out = (float*)d_out;

    hipLaunchKernelGGL(prep_fuse, dim3((WS_TOTAL + 255) / 256), dim3(256), 0, stream,
                       r1_bw, r1_bb, r1_ow, r2_bw, r2_bb, r2_ow, ws);
    hipLaunchKernelGGL(dhsrnn_pipe, dim3(512), dim3(256), 0, stream,
                       x, ws, r1_ob, r2_ob, cw, cb, out);
}

// Round 11
// 105.790 us; speedup vs baseline: 1.7835x; 1.7708x over previous
//
#include <hip/hip_runtime.h>

// SimpleDHSRNN fused forward, round 11: round-8 pipeline structure with
// single-plane FP16 numerics. Fused weights M = (1-alpha)*Wo·Wb precomputed
// fp32 in d_ws (EMA scale prefolded), consumed as single f16; activations
// h1/h2 stored as single f16 plane; bias via MFMA C-init.
// Per wave-step: 4 ds_read_b128, 8 MFMA, ~70 VALU, 8 ds_write_b16, 1 barrier.
// Block = 256 thr = 4 waves, M=16 rows, grid = 512 (2 blocks/CU).

typedef float    f32x4 __attribute__((ext_vector_type(4)));
typedef _Float16 f16x8 __attribute__((ext_vector_type(8)));

#define MFMA16F(a, b, c) __builtin_amdgcn_mfma_f32_16x16x32_f16((a), (b), (c), 0, 0, 0)
#define T_STEPS 196
#define S1S 40    // H1 row stride (f16 elems): 80 B
#define S2S 72    // H2 row stride (f16 elems): 144 B
#define H1B (16 * S1S)
#define H2B (16 * S2S)

// d_ws layout (floats) — all M/c entries pre-scaled by (1-alpha_branch)
#define WS_M1H 0        // [2][32][32]  0.7/0.3 · (W1o_k·W1b_k h-cols)
#define WS_M1X 2048     // [2][32]      scaled x-column
#define WS_C1  2112     // [2][32]      scaled fused bias
#define WS_M2  2176     // [2][64][96]  scaled fused L2 weights
#define WS_C2  14464    // [2][64]      scaled fused bias
#define WS_TOTAL 14592

__global__ void prep_fuse(const float* __restrict__ r1_bw, const float* __restrict__ r1_bb,
                          const float* __restrict__ r1_ow, const float* __restrict__ r2_bw,
                          const float* __restrict__ r2_bb, const float* __restrict__ r2_ow,
                          float* __restrict__ ws)
{
    int idx = blockIdx.x * 256 + threadIdx.x;
    if (idx >= WS_TOTAL) return;
    float acc = 0.0f;
    float sc;
    if (idx < WS_M1X) {                     // M1h[kb][n][k]
        int kb = idx >> 10, rem = idx & 1023, n = rem >> 5, k = rem & 31;
        sc = kb ? 0.3f : 0.7f;
        for (int j = 0; j < 32; ++j)
            acc += r1_ow[n * 64 + kb * 32 + j] * r1_bw[(kb * 32 + j) * 33 + 1 + k];
    } else if (idx < WS_C1) {               // m1x[kb][n]
        int r = idx - WS_M1X; int kb = r >> 5, n = r & 31;
        sc = kb ? 0.3f : 0.7f;
        for (int j = 0; j < 32; ++j)
            acc += r1_ow[n * 64 + kb * 32 + j] * r1_bw[(kb * 32 + j) * 33];
    } else if (idx < WS_M2) {               // c1[kb][n]
        int r = idx - WS_C1; int kb = r >> 5, n = r & 31;
        sc = kb ? 0.3f : 0.7f;
        for (int j = 0; j < 32; ++j)
            acc += r1_ow[n * 64 + kb * 32 + j] * r1_bb[kb * 32 + j];
    } else if (idx < WS_C2) {               // M2[kb][n][k]
        int r = idx - WS_M2; int kb = r / 6144; int r2 = r - kb * 6144;
        int n = r2 / 96, k = r2 - n * 96;
        sc = kb ? 0.3f : 0.7f;
        for (int j = 0; j < 64; ++j)
            acc += r2_ow[n * 128 + kb * 64 + j] * r2_bw[(kb * 64 + j) * 96 + k];
    } else {                                // c2[kb][n]
        int r = idx - WS_C2; int kb = r >> 6, n = r & 63;
        sc = kb ? 0.3f : 0.7f;
        for (int j = 0; j < 64; ++j)
            acc += r2_ow[n * 128 + kb * 64 + j] * r2_bb[kb * 64 + j];
    }
    ws[idx] = acc * sc;
}

// 8 consecutive fp32 -> f16x8 fragment (RNE per-element cvt)
__device__ __forceinline__ f16x8 cvt8(const float* __restrict__ p) {
    f16x8 o;
#pragma unroll
    for (int i = 0; i < 8; ++i) o[i] = (_Float16)p[i];
    return o;
}

__global__ __launch_bounds__(256, 2)
void dhsrnn_f16(const float* __restrict__ x, const float* __restrict__ ws,
                const float* __restrict__ r1_ob, const float* __restrict__ r2_ob,
                const float* __restrict__ cw, const float* __restrict__ cb,
                float* __restrict__ out)
{
    __shared__ __align__(16) _Float16 H1[2 * H1B];
    __shared__ __align__(16) _Float16 H2[2 * H2B];
    __shared__ float XBuf[2][16];
    __shared__ float hcf[16 * 68];   // fp32 h2(T-1) for classifier

    const int tid = threadIdx.x;
    const int w   = tid >> 6;
    const int l   = tid & 63;
    const int li  = l & 15;
    const int g   = l >> 4;
    const int row0 = blockIdx.x * 16;

    // ---- L2 weights (all waves): N=64, K=96, one f16 plane per branch ----
    const int n4 = w * 16 + li;
    f16x8 B2a[3], B2b[3];
#pragma unroll
    for (int kt = 0; kt < 3; ++kt) {
        B2a[kt] = cvt8(ws + WS_M2 + 0 * 6144 + n4 * 96 + kt * 32 + g * 8);
        B2b[kt] = cvt8(ws + WS_M2 + 1 * 6144 + n4 * 96 + kt * 32 + g * 8);
    }
    const float c2a = ws[WS_C2 + n4], c2b = ws[WS_C2 + 64 + n4];
    const float ob2n = r2_ob[n4];
    const f32x4 ci2a = {c2a, c2a, c2a, c2a};
    const f32x4 ci2b = {c2b, c2b, c2b, c2b};

    // ---- L1 weights (waves 2,3): N=32, K=32 ----
    const int n2 = (w & 1) * 16 + li;    // used on w>=2
    f16x8 B1a, B1b;
    float m1xa = 0.f, m1xb = 0.f, c1a = 0.f, c1b = 0.f, ob1n = 0.f;
    if (w >= 2) {
        B1a = cvt8(ws + WS_M1H + 0 * 1024 + n2 * 32 + g * 8);
        B1b = cvt8(ws + WS_M1H + 1 * 1024 + n2 * 32 + g * 8);
        m1xa = ws[WS_M1X + n2];      m1xb = ws[WS_M1X + 32 + n2];
        c1a  = ws[WS_C1 + n2];       c1b  = ws[WS_C1 + 32 + n2];
        ob1n = r1_ob[n2];
    }
    const f32x4 ci1a = {c1a, c1a, c1a, c1a};
    const f32x4 ci1b = {c1b, c1b, c1b, c1b};

    // EMA states (fp32, acc layout m = 4g + r); scale (1-alpha) prefolded in ws
    f32x4 va  = {0.f, 0.f, 0.f, 0.f}, vb  = {0.f, 0.f, 0.f, 0.f};     // layer1 (w>=2)
    f32x4 va2 = {0.f, 0.f, 0.f, 0.f}, vb2 = {0.f, 0.f, 0.f, 0.f};     // layer2 (all)

    // ---- init: zero h2 buf0; stage x(0), x(1) ----
    for (int i = tid; i < H2B; i += 256) H2[i] = (_Float16)0.0f;
    if (tid < 16) {
        XBuf[0][tid] = x[(row0 + tid) * 784];
        XBuf[1][tid] = x[(row0 + tid) * 784 + 4];
    }
    __syncthreads();

    // ---- prologue: h1(0); v(0) = scaled z (s=0) ----
    if (w >= 2) {
        const f32x4 xv = *reinterpret_cast<const f32x4*>(&XBuf[0][4 * g]);
#pragma unroll
        for (int r = 0; r < 4; ++r) {
            int m = 4 * g + r;
            va[r] = c1a + m1xa * xv[r];
            vb[r] = c1b + m1xb * xv[r];
            float h = fmaxf(va[r] + vb[r] + ob1n, 0.0f);
            H1[m * S1S + n2] = (_Float16)h;
        }
    }
    __syncthreads();

    // ---- pipelined loop: iteration t = L2(t) + L1(t+1); one barrier ----
#pragma unroll 1
    for (int t = 0; t < T_STEPS; ++t) {
        const int rb = (t & 1);
        const int wb = rb ^ 1;

        // x(t+2) prefetch (wave 0)
        float xnext = 0.0f;
        if (w == 0 && l < 16 && t < T_STEPS - 2)
            xnext = x[(row0 + l) * 784 + 4 * (t + 2)];

        // A-frags: h1(t), h2(t-1) two k-tiles
        const f16x8 a1  = *reinterpret_cast<const f16x8*>(&H1[rb * H1B + li * S1S + g * 8]);
        const f16x8 a2k1 = *reinterpret_cast<const f16x8*>(&H2[rb * H2B + li * S2S + g * 8]);
        const f16x8 a2k2 = *reinterpret_cast<const f16x8*>(&H2[rb * H2B + li * S2S + 32 + g * 8]);

        // ---- L2(t): all waves, 6 MFMA (3 per branch), bias in C-init ----
        {
            f32x4 d = ci2a;
            f32x4 e = ci2b;
            d = MFMA16F(a1,   B2a[0], d);
            e = MFMA16F(a1,   B2b[0], e);
            d = MFMA16F(a2k1, B2a[1], d);
            e = MFMA16F(a2k1, B2b[1], e);
            d = MFMA16F(a2k2, B2a[2], d);
            e = MFMA16F(a2k2, B2b[2], e);
#pragma unroll
            for (int r = 0; r < 4; ++r) {
                int m = 4 * g + r;
                va2[r] = fmaf(0.3f, va2[r], d[r]);
                vb2[r] = fmaf(0.7f, vb2[r], e[r]);
                float h = fmaxf(va2[r] + vb2[r] + ob2n, 0.0f);
                H2[wb * H2B + m * S2S + n4] = (_Float16)h;
                if (t == T_STEPS - 1) hcf[m * 68 + n4] = h;
            }
        }

        // ---- L1(t+1): waves 2,3, 2 MFMA, reuse a1 ----
        if (w >= 2 && t < T_STEPS - 1) {
            f32x4 p = ci1a;
            f32x4 q = ci1b;
            p = MFMA16F(a1, B1a, p);
            q = MFMA16F(a1, B1b, q);
            const f32x4 xv = *reinterpret_cast<const f32x4*>(&XBuf[wb][4 * g]);  // x(t+1)
#pragma unroll
            for (int r = 0; r < 4; ++r) {
                int m = 4 * g + r;
                float za = fmaf(m1xa, xv[r], p[r]);
                float zb = fmaf(m1xb, xv[r], q[r]);
                va[r] = fmaf(0.3f, va[r], za);
                vb[r] = fmaf(0.7f, vb[r], zb);
                float h = fmaxf(va[r] + vb[r] + ob1n, 0.0f);
                H1[wb * H1B + m * S1S + n2] = (_Float16)h;
            }
        }

        // commit x(t+2) into the buffer read two iterations from now
        if (w == 0 && l < 16 && t < T_STEPS - 2) XBuf[rb][l] = xnext;

        __syncthreads();   // h1(t+1), h2(t), x(t+2) ready
    }

    // ---- classifier: out[b][c] = h2 . cw[c] + cb[c] ----
    {
        const int c = tid >> 4;
        const int e = tid & 15;
        if (c < 10) {
            float acc = cb[c];
#pragma unroll 4
            for (int dd = 0; dd < 64; ++dd)
                acc += hcf[e * 68 + dd] * cw[c * 64 + dd];
            out[(row0 + e) * 10 + c] = acc;
        }
    }
}

extern "C" void kernel_launch(void* const* d_in, const int* in_sizes, int n_in,
                              void* d_out, int out_size, void* d_ws, size_t ws_size,
                              hipStream_t stream) {
    const float* x     = (const float*)d_in[0];
    const float* r1_bw = (const float*)d_in[1];
    const float* r1_bb = (const float*)d_in[2];
    const float* r1_ow = (const float*)d_in[3];
    const float* r1_ob = (const float*)d_in[4];
    const float* r2_bw = (const float*)d_in[5];
    const float* r2_bb = (const float*)d_in[6];
    const float* r2_ow = (const float*)d_in[7];
    const float* r2_ob = (const float*)d_in[8];
    const float* cw    = (const float*)d_in[9];
    const float* cb    = (const float*)d_in[10];
    float* ws  = (float*)d_ws;
    float* out = (float*)d_out;

    hipLaunchKernelGGL(prep_fuse, dim3((WS_TOTAL + 255) / 256), dim3(256), 0, stream,
                       r1_bw, r1_bb, r1_ow, r2_bw, r2_bb, r2_ow, ws);
    hipLaunchKernelGGL(dhsrnn_f16, dim3(512), dim3(256), 0, stream,
                       x, ws, r1_ob, r2_ob, cw, cb, out);
}

// Round 12
// 89.270 us; speedup vs baseline: 2.1135x; 1.1850x over previous
//
#include <hip/hip_runtime.h>

// SimpleDHSRNN fused forward, round 12: r11 f16 single-plane numerics +
// 2-step unroll (compile-time rb/wb), peeled final step, setprio on MFMA.
// Block = 256 thr = 4 waves, M=16 rows, grid = 512 (2 blocks/CU).

typedef float    f32x4 __attribute__((ext_vector_type(4)));
typedef _Float16 f16x8 __attribute__((ext_vector_type(8)));

#define MFMA16F(a, b, c) __builtin_amdgcn_mfma_f32_16x16x32_f16((a), (b), (c), 0, 0, 0)
#define T_STEPS 196
#define S1S 40    // H1 row stride (f16 elems): 80 B
#define S2S 72    // H2 row stride (f16 elems): 144 B
#define H1B (16 * S1S)
#define H2B (16 * S2S)

// d_ws layout (floats) — all M/c entries pre-scaled by (1-alpha_branch)
#define WS_M1H 0        // [2][32][32]
#define WS_M1X 2048     // [2][32]
#define WS_C1  2112     // [2][32]
#define WS_M2  2176     // [2][64][96]
#define WS_C2  14464    // [2][64]
#define WS_TOTAL 14592

__global__ void prep_fuse(const float* __restrict__ r1_bw, const float* __restrict__ r1_bb,
                          const float* __restrict__ r1_ow, const float* __restrict__ r2_bw,
                          const float* __restrict__ r2_bb, const float* __restrict__ r2_ow,
                          float* __restrict__ ws)
{
    int idx = blockIdx.x * 256 + threadIdx.x;
    if (idx >= WS_TOTAL) return;
    float acc = 0.0f;
    float sc;
    if (idx < WS_M1X) {                     // M1h[kb][n][k]
        int kb = idx >> 10, rem = idx & 1023, n = rem >> 5, k = rem & 31;
        sc = kb ? 0.3f : 0.7f;
        for (int j = 0; j < 32; ++j)
            acc += r1_ow[n * 64 + kb * 32 + j] * r1_bw[(kb * 32 + j) * 33 + 1 + k];
    } else if (idx < WS_C1) {               // m1x[kb][n]
        int r = idx - WS_M1X; int kb = r >> 5, n = r & 31;
        sc = kb ? 0.3f : 0.7f;
        for (int j = 0; j < 32; ++j)
            acc += r1_ow[n * 64 + kb * 32 + j] * r1_bw[(kb * 32 + j) * 33];
    } else if (idx < WS_M2) {               // c1[kb][n]
        int r = idx - WS_C1; int kb = r >> 5, n = r & 31;
        sc = kb ? 0.3f : 0.7f;
        for (int j = 0; j < 32; ++j)
            acc += r1_ow[n * 64 + kb * 32 + j] * r1_bb[kb * 32 + j];
    } else if (idx < WS_C2) {               // M2[kb][n][k]
        int r = idx - WS_M2; int kb = r / 6144; int r2 = r - kb * 6144;
        int n = r2 / 96, k = r2 - n * 96;
        sc = kb ? 0.3f : 0.7f;
        for (int j = 0; j < 64; ++j)
            acc += r2_ow[n * 128 + kb * 64 + j] * r2_bw[(kb * 64 + j) * 96 + k];
    } else {                                // c2[kb][n]
        int r = idx - WS_C2; int kb = r >> 6, n = r & 63;
        sc = kb ? 0.3f : 0.7f;
        for (int j = 0; j < 64; ++j)
            acc += r2_ow[n * 128 + kb * 64 + j] * r2_bb[kb * 64 + j];
    }
    ws[idx] = acc * sc;
}

__device__ __forceinline__ f16x8 cvt8(const float* __restrict__ p) {
    f16x8 o;
#pragma unroll
    for (int i = 0; i < 8; ++i) o[i] = (_Float16)p[i];
    return o;
}

__global__ __launch_bounds__(256, 2)
void dhsrnn_f16(const float* __restrict__ x, const float* __restrict__ ws,
                const float* __restrict__ r1_ob, const float* __restrict__ r2_ob,
                const float* __restrict__ cw, const float* __restrict__ cb,
                float* __restrict__ out)
{
    __shared__ __align__(16) _Float16 H1[2 * H1B];
    __shared__ __align__(16) _Float16 H2[2 * H2B];
    __shared__ float XBuf[2][16];
    __shared__ float hcf[16 * 68];   // fp32 h2(T-1) for classifier

    const int tid = threadIdx.x;
    const int w   = tid >> 6;
    const int l   = tid & 63;
    const int li  = l & 15;
    const int g   = l >> 4;
    const int row0 = blockIdx.x * 16;

    // ---- L2 weights (all waves): N=64, K=96 ----
    const int n4 = w * 16 + li;
    f16x8 B2a[3], B2b[3];
#pragma unroll
    for (int kt = 0; kt < 3; ++kt) {
        B2a[kt] = cvt8(ws + WS_M2 + 0 * 6144 + n4 * 96 + kt * 32 + g * 8);
        B2b[kt] = cvt8(ws + WS_M2 + 1 * 6144 + n4 * 96 + kt * 32 + g * 8);
    }
    const float c2a = ws[WS_C2 + n4], c2b = ws[WS_C2 + 64 + n4];
    const float ob2n = r2_ob[n4];
    const f32x4 ci2a = {c2a, c2a, c2a, c2a};
    const f32x4 ci2b = {c2b, c2b, c2b, c2b};

    // ---- L1 weights (waves 2,3): N=32, K=32 ----
    const int n2 = (w & 1) * 16 + li;
    f16x8 B1a, B1b;
    float m1xa = 0.f, m1xb = 0.f, c1a = 0.f, c1b = 0.f, ob1n = 0.f;
    if (w >= 2) {
        B1a = cvt8(ws + WS_M1H + 0 * 1024 + n2 * 32 + g * 8);
        B1b = cvt8(ws + WS_M1H + 1 * 1024 + n2 * 32 + g * 8);
        m1xa = ws[WS_M1X + n2];      m1xb = ws[WS_M1X + 32 + n2];
        c1a  = ws[WS_C1 + n2];       c1b  = ws[WS_C1 + 32 + n2];
        ob1n = r1_ob[n2];
    }
    const f32x4 ci1a = {c1a, c1a, c1a, c1a};
    const f32x4 ci1b = {c1b, c1b, c1b, c1b};

    // EMA states (fp32, acc layout m = 4g + r)
    f32x4 va  = {0.f, 0.f, 0.f, 0.f}, vb  = {0.f, 0.f, 0.f, 0.f};
    f32x4 va2 = {0.f, 0.f, 0.f, 0.f}, vb2 = {0.f, 0.f, 0.f, 0.f};

    // ---- init ----
    for (int i = tid; i < H2B; i += 256) H2[i] = (_Float16)0.0f;
    if (tid < 16) {
        XBuf[0][tid] = x[(row0 + tid) * 784];
        XBuf[1][tid] = x[(row0 + tid) * 784 + 4];
    }
    __syncthreads();

    // ---- prologue: h1(0) ----
    if (w >= 2) {
        const f32x4 xv = *reinterpret_cast<const f32x4*>(&XBuf[0][4 * g]);
#pragma unroll
        for (int r = 0; r < 4; ++r) {
            int m = 4 * g + r;
            va[r] = c1a + m1xa * xv[r];
            vb[r] = c1b + m1xb * xv[r];
            float h = fmaxf(va[r] + vb[r] + ob1n, 0.0f);
            H1[m * S1S + n2] = (_Float16)h;
        }
    }
    __syncthreads();

    // one step, rb/wb compile-time after inlining; no hcf path in hot body
    auto step = [&](const int rb, const int t) {
        const int wb = rb ^ 1;

        float xnext = 0.0f;
        if (w == 0 && l < 16 && t < T_STEPS - 2)
            xnext = x[(row0 + l) * 784 + 4 * (t + 2)];

        const f16x8 a1   = *reinterpret_cast<const f16x8*>(&H1[rb * H1B + li * S1S + g * 8]);
        const f16x8 a2k1 = *reinterpret_cast<const f16x8*>(&H2[rb * H2B + li * S2S + g * 8]);
        const f16x8 a2k2 = *reinterpret_cast<const f16x8*>(&H2[rb * H2B + li * S2S + 32 + g * 8]);

        // L2(t): bias rides in as the C operand of the first MFMA (no movs)
        __builtin_amdgcn_s_setprio(1);
        f32x4 d = MFMA16F(a1, B2a[0], ci2a);
        f32x4 e = MFMA16F(a1, B2b[0], ci2b);
        d = MFMA16F(a2k1, B2a[1], d);
        e = MFMA16F(a2k1, B2b[1], e);
        d = MFMA16F(a2k2, B2a[2], d);
        e = MFMA16F(a2k2, B2b[2], e);
        __builtin_amdgcn_s_setprio(0);
#pragma unroll
        for (int r = 0; r < 4; ++r) {
            int m = 4 * g + r;
            va2[r] = fmaf(0.3f, va2[r], d[r]);
            vb2[r] = fmaf(0.7f, vb2[r], e[r]);
            float h = fmaxf(va2[r] + vb2[r] + ob2n, 0.0f);
            H2[wb * H2B + m * S2S + n4] = (_Float16)h;
        }

        // L1(t+1): waves 2,3 (t <= 194 always when called from the hot loop)
        if (w >= 2) {
            __builtin_amdgcn_s_setprio(1);
            f32x4 p = MFMA16F(a1, B1a, ci1a);
            f32x4 q = MFMA16F(a1, B1b, ci1b);
            __builtin_amdgcn_s_setprio(0);
            const f32x4 xv = *reinterpret_cast<const f32x4*>(&XBuf[wb][4 * g]);
#pragma unroll
            for (int r = 0; r < 4; ++r) {
                int m = 4 * g + r;
                float za = fmaf(m1xa, xv[r], p[r]);
                float zb = fmaf(m1xb, xv[r], q[r]);
                va[r] = fmaf(0.3f, va[r], za);
                vb[r] = fmaf(0.7f, vb[r], zb);
                float h = fmaxf(va[r] + vb[r] + ob1n, 0.0f);
                H1[wb * H1B + m * S1S + n2] = (_Float16)h;
            }
        }

        if (w == 0 && l < 16 && t < T_STEPS - 2) XBuf[rb][l] = xnext;
        __syncthreads();
    };

    // ---- hot loop: t = 0..193 in unrolled pairs, then t = 194 ----
#pragma unroll 1
    for (int tp = 0; tp < (T_STEPS - 2) / 2; ++tp) {   // 97 pairs -> t=0..193
        step(0, 2 * tp);
        step(1, 2 * tp + 1);
    }
    step(0, T_STEPS - 2);   // t=194 (rb=0): computes h2(194), h1(195)

    // ---- peeled final step t=195 (rb=1): h2(195) -> hcf only ----
    {
        const int rb = 1;
        const f16x8 a1   = *reinterpret_cast<const f16x8*>(&H1[rb * H1B + li * S1S + g * 8]);
        const f16x8 a2k1 = *reinterpret_cast<const f16x8*>(&H2[rb * H2B + li * S2S + g * 8]);
        const f16x8 a2k2 = *reinterpret_cast<const f16x8*>(&H2[rb * H2B + li * S2S + 32 + g * 8]);
        f32x4 d = MFMA16F(a1, B2a[0], ci2a);
        f32x4 e = MFMA16F(a1, B2b[0], ci2b);
        d = MFMA16F(a2k1, B2a[1], d);
        e = MFMA16F(a2k1, B2b[1], e);
        d = MFMA16F(a2k2, B2a[2], d);
        e = MFMA16F(a2k2, B2b[2], e);
#pragma unroll
        for (int r = 0; r < 4; ++r) {
            int m = 4 * g + r;
            va2[r] = fmaf(0.3f, va2[r], d[r]);
            vb2[r] = fmaf(0.7f, vb2[r], e[r]);
            hcf[m * 68 + n4] = fmaxf(va2[r] + vb2[r] + ob2n, 0.0f);
        }
    }
    __syncthreads();

    // ---- classifier ----
    {
        const int c = tid >> 4;
        const int e = tid & 15;
        if (c < 10) {
            float acc = cb[c];
#pragma unroll 4
            for (int dd = 0; dd < 64; ++dd)
                acc += hcf[e * 68 + dd] * cw[c * 64 + dd];
            out[(row0 + e) * 10 + c] = acc;
        }
    }
}

extern "C" void kernel_launch(void* const* d_in, const int* in_sizes, int n_in,
                              void* d_out, int out_size, void* d_ws, size_t ws_size,
                              hipStream_t stream) {
    const float* x     = (const float*)d_in[0];
    const float* r1_bw = (const float*)d_in[1];
    const float* r1_bb = (const float*)d_in[2];
    const float* r1_ow = (const float*)d_in[3];
    const float* r1_ob = (const float*)d_in[4];
    const float* r2_bw = (const float*)d_in[5];
    const float* r2_bb = (const float*)d_in[6];
    const float* r2_ow = (const float*)d_in[7];
    const float* r2_ob = (const float*)d_in[8];
    const float* cw    = (const float*)d_in[9];
    const float* cb    = (const float*)d_in[10];
    float* ws  = (float*)d_ws;
    float* out = (float*)d_out;

    hipLaunchKernelGGL(prep_fuse, dim3((WS_TOTAL + 255) / 256), dim3(256), 0, stream,
                       r1_bw, r1_bb, r1_ow, r2_bw, r2_bb, r2_ow, ws);
    hipLaunchKernelGGL(dhsrnn_f16, dim3(512), dim3(256), 0, stream,
                       x, ws, r1_ob, r2_ob, cw, cb, out);
}